// Round 8
// baseline (13429.176 us; speedup 1.0000x reference)
//
#include <hip/hip_runtime.h>
#include <math.h>

typedef float v2f __attribute__((ext_vector_type(2)));
typedef float v4f __attribute__((ext_vector_type(4)));

#define NPTS   2048
#define NPAIR  1024
#define BATCH  16
#define EPS    0.0025f                      // blur=0.05, p=2 -> eps = 0.05^2
#define SCALE  577.0780163555853f           // (1/EPS) * log2(e)
#define INV_SCALE (1.0f / SCALE)
#define LN2    0.6931471805599453f
#define LN_N   7.6246189861593985f          // ln(2048)
#define ITERS  50
#define RPT    4                            // rows per thread
#define LPR    64                           // one full wave per row-group
#define NGRP   8                            // groups per 512-thread block
#define RPB    32                           // rows per block (8 grp * 4)
#define GRID_X (NPTS / RPB)                 // 64 -> 1024 blocks = 4/CU, 32 waves/CU
#define BLK    512
#define NEG_INF (-3.0e38f)

__device__ __forceinline__ float exp2fast(float x) { return __builtin_amdgcn_exp2f(x); }
__device__ __forceinline__ float log2fast(float x) { return __builtin_amdgcn_logf(x); }
__device__ __forceinline__ v2f bc2(float v) { v2f r; r.x = v; r.y = v; return r; }
__device__ __forceinline__ v2f vmax2(v2f a, v2f b) { return __builtin_elementwise_max(a, b); }

// Async global->LDS staging of 2048 v4f (32 KB), 512 threads, linear dest.
__device__ __forceinline__ void stage_async(const v4f* __restrict__ src, v4f* dst, int tid)
{
    const int lane = tid & 63;
    const int wid  = tid >> 6;               // 0..7
    #pragma unroll
    for (int i = 0; i < 4; ++i) {
        const int m0 = i * 512 + wid * 64;
        __builtin_amdgcn_global_load_lds(
            (const __attribute__((address_space(1))) void*)(src + m0 + lane),
            (__attribute__((address_space(3))) void*)(dst + m0), 16, 0, 0);
    }
}

// Pair-interleaved packing:
// rec[p]        = (x_e, x_o, y_e, y_o) * SCALE       (e = point 2p, o = 2p+1)
// rec[NPAIR+p]  = (z_e, z_o, w_e, w_o), w = -0.5*SCALE*|p|^2
// Seeds FoldX/FoldY coord records once (sink_step rewrites only Z-records).
__global__ __launch_bounds__(256) void pack_geo(
    const float* __restrict__ X, const float* __restrict__ Y,
    v4f* __restrict__ Xg, v4f* __restrict__ Yg,
    v4f* __restrict__ FoldX, v4f* __restrict__ FoldY)
{
    const int b = blockIdx.y;
    const int p = blockIdx.x * 256 + threadIdx.x;
    {
        const float* s = X + (size_t)b * NPTS * 3 + 6 * p;
        float a0=s[0],a1=s[1],a2=s[2],a3=s[3],a4=s[4],a5=s[5];
        float we = -0.5f*SCALE*(a0*a0+a1*a1+a2*a2);
        float wo = -0.5f*SCALE*(a3*a3+a4*a4+a5*a5);
        v4f u; u.x=a0*SCALE; u.y=a3*SCALE; u.z=a1*SCALE; u.w=a4*SCALE;
        v4f v; v.x=a2*SCALE; v.y=a5*SCALE; v.z=we; v.w=wo;
        Xg[(size_t)b*NPTS + p] = u;         Xg[(size_t)b*NPTS + NPAIR + p] = v;
        FoldX[(size_t)b*NPTS + p] = u;      FoldX[(size_t)b*NPTS + NPAIR + p] = v;
    }
    {
        const float* s = Y + (size_t)b * NPTS * 3 + 6 * p;
        float a0=s[0],a1=s[1],a2=s[2],a3=s[3],a4=s[4],a5=s[5];
        float we = -0.5f*SCALE*(a0*a0+a1*a1+a2*a2);
        float wo = -0.5f*SCALE*(a3*a3+a4*a4+a5*a5);
        v4f u; u.x=a0*SCALE; u.y=a3*SCALE; u.z=a1*SCALE; u.w=a4*SCALE;
        v4f v; v.x=a2*SCALE; v.y=a5*SCALE; v.z=we; v.w=wo;
        Yg[(size_t)b*NPTS + p] = u;         Yg[(size_t)b*NPTS + NPAIR + p] = v;
        FoldY[(size_t)b*NPTS + p] = u;      FoldY[(size_t)b*NPTS + NPAIR + p] = v;
    }
}

// One Sinkhorn half-update: 512 threads, 8 row-groups x (1 wave, 4 rows).
// Cols staged (async DMA) from stageSrc whose .w folds the current potential.
// Writes potentials Pout and the 2 changed Z-records of FoldOut.
// partA != nullptr (first f-update, pristine cols): emit chamfer dir-A partials.
__global__ __launch_bounds__(BLK, 8) void sink_step(
    const v4f* __restrict__ geoR, const v4f* __restrict__ stageSrc,
    float* __restrict__ Pout, v4f* __restrict__ FoldOut, float* __restrict__ partA)
{
    __shared__ v4f S[2 * NPAIR];
    __shared__ float gsum[NGRP];
    v4f* PX = S;
    v4f* PZ = S + NPAIR;

    const int b = blockIdx.y, tile = blockIdx.x, tid = threadIdx.x;
    const int sub = tid & (LPR - 1);
    const int grp = tid >> 6;
    const int row0 = tile * RPB + grp * RPT;

    stage_async(stageSrc + (size_t)b * NPTS, S, tid);

    // rows (pristine, pair-packed): pair q holds rows 2q,2q+1
    const v4f* gR = geoR + (size_t)b * NPTS;
    const int q = row0 >> 1;
    v4f A = gR[q], B = gR[NPAIR + q], C = gR[q + 1], D = gR[NPAIR + q + 1];
    v2f xb[RPT], yb[RPT], zb[RPT];
    float a2[RPT], mx[RPT], s[RPT];
    xb[0]=bc2(A.x*INV_SCALE); yb[0]=bc2(A.z*INV_SCALE); zb[0]=bc2(B.x*INV_SCALE); a2[0]=B.z;
    xb[1]=bc2(A.y*INV_SCALE); yb[1]=bc2(A.w*INV_SCALE); zb[1]=bc2(B.y*INV_SCALE); a2[1]=B.w;
    xb[2]=bc2(C.x*INV_SCALE); yb[2]=bc2(C.z*INV_SCALE); zb[2]=bc2(D.x*INV_SCALE); a2[2]=D.z;
    xb[3]=bc2(C.y*INV_SCALE); yb[3]=bc2(C.w*INV_SCALE); zb[3]=bc2(D.y*INV_SCALE); a2[3]=D.w;
    #pragma unroll
    for (int rr = 0; rr < RPT; ++rr) { mx[rr] = NEG_INF; s[rr] = 0.0f; }

    asm volatile("s_waitcnt vmcnt(0)" ::: "memory");
    __syncthreads();

    // online-LSE over 4 column-pairs (8 cols) per iteration, packed math
    #pragma unroll 2
    for (int k = sub; k < NPAIR; k += 4 * LPR) {
        v4f A0 = PX[k],         Z0 = PZ[k];
        v4f A1 = PX[k + LPR],   Z1 = PZ[k + LPR];
        v4f A2 = PX[k + 2*LPR], Z2 = PZ[k + 2*LPR];
        v4f A3 = PX[k + 3*LPR], Z3 = PZ[k + 3*LPR];
        #pragma unroll
        for (int rr = 0; rr < RPT; ++rr) {
            v2f t0 = xb[rr]*A0.xy + yb[rr]*A0.zw + zb[rr]*Z0.xy + Z0.zw;
            v2f t1 = xb[rr]*A1.xy + yb[rr]*A1.zw + zb[rr]*Z1.xy + Z1.zw;
            v2f t2 = xb[rr]*A2.xy + yb[rr]*A2.zw + zb[rr]*Z2.xy + Z2.zw;
            v2f t3 = xb[rr]*A3.xy + yb[rr]*A3.zw + zb[rr]*Z3.xy + Z3.zw;
            v2f cm = vmax2(vmax2(t0, t1), vmax2(t2, t3));
            float mc = fmaxf(cm.x, cm.y);
            float nm = fmaxf(mx[rr], mc);
            float er = exp2fast(mx[rr] - nm);
            v2f nm2 = bc2(nm);
            v2f u0 = t0 - nm2, u1 = t1 - nm2, u2 = t2 - nm2, u3 = t3 - nm2;
            float e0 = exp2fast(u0.x), e1 = exp2fast(u0.y);
            float e2 = exp2fast(u1.x), e3 = exp2fast(u1.y);
            float e4 = exp2fast(u2.x), e5 = exp2fast(u2.y);
            float e6 = exp2fast(u3.x), e7 = exp2fast(u3.y);
            s[rr]  = fmaf(s[rr], er, ((e0+e1)+(e2+e3)) + ((e4+e5)+(e6+e7)));
            mx[rr] = nm;
        }
    }

    // two-phase merge across 64 lanes: max-reduce, one rescale, sum-reduce
    float om[RPT];
    #pragma unroll
    for (int rr = 0; rr < RPT; ++rr) om[rr] = mx[rr];
    #pragma unroll
    for (int d = 1; d < LPR; d <<= 1) {
        #pragma unroll
        for (int rr = 0; rr < RPT; ++rr) mx[rr] = fmaxf(mx[rr], __shfl_xor(mx[rr], d));
    }
    #pragma unroll
    for (int rr = 0; rr < RPT; ++rr) s[rr] *= exp2fast(om[rr] - mx[rr]);
    #pragma unroll
    for (int d = 1; d < LPR; d <<= 1) {
        #pragma unroll
        for (int rr = 0; rr < RPT; ++rr) s[rr] += __shfl_xor(s[rr], d);
    }

    if (sub == 0) {
        float pot[RPT];
        #pragma unroll
        for (int rr = 0; rr < RPT; ++rr)
            pot[rr] = EPS * (LN_N - LN2 * (a2[rr] + mx[rr] + log2fast(s[rr])));
        v4f pv; pv.x = pot[0]; pv.y = pot[1]; pv.z = pot[2]; pv.w = pot[3];
        *(v4f*)(Pout + (size_t)b * NPTS + row0) = pv;     // row0 % 4 == 0

        // fold-forward: only the 2 changed Z-records (coords seeded by pack_geo)
        v4f* fo = FoldOut + (size_t)b * NPTS;
        v4f u;
        u.x = zb[0].x*SCALE; u.y = zb[1].x*SCALE;
        u.z = fmaf(pot[0], SCALE, a2[0]); u.w = fmaf(pot[1], SCALE, a2[1]);
        fo[NPAIR + q] = u;
        u.x = zb[2].x*SCALE; u.y = zb[3].x*SCALE;
        u.z = fmaf(pot[2], SCALE, a2[2]); u.w = fmaf(pot[3], SCALE, a2[3]);
        fo[NPAIR + q + 1] = u;

        if (partA) {
            float c = 0.0f;
            #pragma unroll
            for (int rr = 0; rr < RPT; ++rr)
                c += fmaxf(-2.0f * INV_SCALE * (a2[rr] + mx[rr]), 0.0f);
            gsum[grp] = c;
        }
    }
    if (partA) {
        __syncthreads();
        if (tid == 0) {
            float t = 0.0f;
            #pragma unroll
            for (int i = 0; i < NGRP; ++i) t += gsum[i];
            partA[b * GRID_X + tile] = t;
        }
    }
}

// Chamfer dir-B: rows = Y pristine, cols = X pristine. Max-only scan.
__global__ __launch_bounds__(BLK, 8) void chamfer_b(
    const v4f* __restrict__ geoR, const v4f* __restrict__ stageSrc,
    float* __restrict__ part)
{
    __shared__ v4f S[2 * NPAIR];
    __shared__ float gsum[NGRP];
    v4f* PX = S;
    v4f* PZ = S + NPAIR;
    const int b = blockIdx.y, tile = blockIdx.x, tid = threadIdx.x;
    const int sub = tid & (LPR - 1);
    const int grp = tid >> 6;
    const int row0 = tile * RPB + grp * RPT;

    stage_async(stageSrc + (size_t)b * NPTS, S, tid);

    const v4f* gR = geoR + (size_t)b * NPTS;
    const int q = row0 >> 1;
    v4f A = gR[q], B = gR[NPAIR + q], C = gR[q + 1], D = gR[NPAIR + q + 1];
    v2f xb[RPT], yb[RPT], zb[RPT];
    float a2[RPT], mx[RPT];
    xb[0]=bc2(A.x*INV_SCALE); yb[0]=bc2(A.z*INV_SCALE); zb[0]=bc2(B.x*INV_SCALE); a2[0]=B.z;
    xb[1]=bc2(A.y*INV_SCALE); yb[1]=bc2(A.w*INV_SCALE); zb[1]=bc2(B.y*INV_SCALE); a2[1]=B.w;
    xb[2]=bc2(C.x*INV_SCALE); yb[2]=bc2(C.z*INV_SCALE); zb[2]=bc2(D.x*INV_SCALE); a2[2]=D.z;
    xb[3]=bc2(C.y*INV_SCALE); yb[3]=bc2(C.w*INV_SCALE); zb[3]=bc2(D.y*INV_SCALE); a2[3]=D.w;
    #pragma unroll
    for (int rr = 0; rr < RPT; ++rr) mx[rr] = NEG_INF;

    asm volatile("s_waitcnt vmcnt(0)" ::: "memory");
    __syncthreads();

    #pragma unroll 2
    for (int k = sub; k < NPAIR; k += 4 * LPR) {
        v4f A0 = PX[k],         Z0 = PZ[k];
        v4f A1 = PX[k + LPR],   Z1 = PZ[k + LPR];
        v4f A2 = PX[k + 2*LPR], Z2 = PZ[k + 2*LPR];
        v4f A3 = PX[k + 3*LPR], Z3 = PZ[k + 3*LPR];
        #pragma unroll
        for (int rr = 0; rr < RPT; ++rr) {
            v2f t0 = xb[rr]*A0.xy + yb[rr]*A0.zw + zb[rr]*Z0.xy + Z0.zw;
            v2f t1 = xb[rr]*A1.xy + yb[rr]*A1.zw + zb[rr]*Z1.xy + Z1.zw;
            v2f t2 = xb[rr]*A2.xy + yb[rr]*A2.zw + zb[rr]*Z2.xy + Z2.zw;
            v2f t3 = xb[rr]*A3.xy + yb[rr]*A3.zw + zb[rr]*Z3.xy + Z3.zw;
            v2f cm = vmax2(vmax2(t0, t1), vmax2(t2, t3));
            mx[rr] = fmaxf(mx[rr], fmaxf(cm.x, cm.y));
        }
    }
    #pragma unroll
    for (int d = 1; d < LPR; d <<= 1) {
        #pragma unroll
        for (int rr = 0; rr < RPT; ++rr) mx[rr] = fmaxf(mx[rr], __shfl_xor(mx[rr], d));
    }
    if (sub == 0) {
        float c = 0.0f;
        #pragma unroll
        for (int rr = 0; rr < RPT; ++rr)
            c += fmaxf(-2.0f * INV_SCALE * (a2[rr] + mx[rr]), 0.0f);
        gsum[grp] = c;
    }
    __syncthreads();
    if (tid == 0) {
        float t = 0.0f;
        #pragma unroll
        for (int i = 0; i < NGRP; ++i) t += gsum[i];
        part[b * GRID_X + tile] = t;
    }
}

__global__ void finalize(const float* __restrict__ F, const float* __restrict__ G,
                         const float* __restrict__ part, float* __restrict__ out)
{
    const int b = blockIdx.x, tid = threadIdx.x;
    float sf = 0.0f, sg = 0.0f, sc = 0.0f;
    for (int i = tid; i < NPTS; i += 256) {
        sf += F[(size_t)b * NPTS + i];
        sg += G[(size_t)b * NPTS + i];
    }
    for (int i = tid; i < 2 * GRID_X * BATCH; i += 256) sc += part[i];
    #pragma unroll
    for (int d = 1; d < 64; d <<= 1) {
        sf += __shfl_xor(sf, d); sg += __shfl_xor(sg, d); sc += __shfl_xor(sc, d);
    }
    __shared__ float wf[4], wg[4], wc[4];
    const int w = tid >> 6;
    if ((tid & 63) == 0) { wf[w] = sf; wg[w] = sg; wc[w] = sc; }
    __syncthreads();
    if (tid == 0) {
        float tf = wf[0] + wf[1] + wf[2] + wf[3];
        float tg = wg[0] + wg[1] + wg[2] + wg[3];
        float tc = wc[0] + wc[1] + wc[2] + wc[3];
        float emd = (tf + tg) * (1.0f / NPTS);
        float cd  = tc * (1.0f / (BATCH * NPTS));
        out[b] = 0.5f * cd + 0.5f * emd;
    }
}

extern "C" void kernel_launch(void* const* d_in, const int* in_sizes, int n_in,
                              void* d_out, int out_size, void* d_ws, size_t ws_size,
                              hipStream_t stream)
{
    const float* Xtrue = (const float*)d_in[0];   // y_true: rows of D
    const float* Ypred = (const float*)d_in[1];   // y_pred: cols of D

    float* F    = (float*)d_ws;                   // [16][2048]
    float* G    = F + BATCH * NPTS;               // [16][2048]
    float* part = G + BATCH * NPTS;               // [2048]
    v4f*  Xg    = (v4f*)(part + 2 * GRID_X * BATCH);   // 16B-aligned
    v4f*  Yg    = Xg + (size_t)BATCH * NPTS;
    v4f*  FoldX = Yg + (size_t)BATCH * NPTS;
    v4f*  FoldY = FoldX + (size_t)BATCH * NPTS;

    pack_geo<<<dim3(NPAIR / 256, BATCH), dim3(256), 0, stream>>>(
        Xtrue, Ypred, Xg, Yg, FoldX, FoldY);

    dim3 grid(GRID_X, BATCH), blk(BLK);
    chamfer_b<<<grid, blk, 0, stream>>>(Yg, Xg, part + GRID_X * BATCH);

    // iter 0: f-update stages pristine Yg (pot=0) and emits chamfer dir-A
    sink_step<<<grid, blk, 0, stream>>>(Xg, Yg, F, FoldX, part);
    sink_step<<<grid, blk, 0, stream>>>(Yg, FoldX, G, FoldY, nullptr);
    for (int it = 1; it < ITERS; ++it) {
        sink_step<<<grid, blk, 0, stream>>>(Xg, FoldY, F, FoldX, nullptr);
        sink_step<<<grid, blk, 0, stream>>>(Yg, FoldX, G, FoldY, nullptr);
    }
    finalize<<<dim3(BATCH), dim3(256), 0, stream>>>(F, G, part, (float*)d_out);
}

// Round 9
// 2150.885 us; speedup vs baseline: 6.2436x; 6.2436x over previous
//
#include <hip/hip_runtime.h>
#include <math.h>

typedef float v2f __attribute__((ext_vector_type(2)));
typedef float v4f __attribute__((ext_vector_type(4)));

#define NPTS   2048
#define NPAIR  1024
#define BATCH  16
#define EPS    0.0025f                      // blur=0.05, p=2 -> eps = 0.05^2
#define SCALE  577.0780163555853f           // (1/EPS) * log2(e)
#define INV_SCALE (1.0f / SCALE)
#define LN2    0.6931471805599453f
#define LN_N   7.6246189861593985f          // ln(2048)
#define ITERS  50
#define RPT    4                            // rows per thread
#define LPR    64                           // one full wave per row-group
#define NGRP   8                            // groups per 512-thread block
#define RPB    32                           // rows per block (8 grp * 4)
#define GRID_X (NPTS / RPB)                 // 64 -> 1024 blocks = 4/CU
#define BLK    512
#define NEG_INF (-3.0e38f)

__device__ __forceinline__ float exp2fast(float x) { return __builtin_amdgcn_exp2f(x); }
__device__ __forceinline__ float log2fast(float x) { return __builtin_amdgcn_logf(x); }
__device__ __forceinline__ v2f bc2(float v) { v2f r; r.x = v; r.y = v; return r; }
__device__ __forceinline__ v2f vmax2(v2f a, v2f b) { return __builtin_elementwise_max(a, b); }

// Async global->LDS staging of 2048 v4f (32 KB), 512 threads, linear dest.
__device__ __forceinline__ void stage_async(const v4f* __restrict__ src, v4f* dst, int tid)
{
    const int lane = tid & 63;
    const int wid  = tid >> 6;               // 0..7
    #pragma unroll
    for (int i = 0; i < 4; ++i) {
        const int m0 = i * 512 + wid * 64;
        __builtin_amdgcn_global_load_lds(
            (const __attribute__((address_space(1))) void*)(src + m0 + lane),
            (__attribute__((address_space(3))) void*)(dst + m0), 16, 0, 0);
    }
}

// Pair-interleaved packing:
// rec[p]        = (x_e, x_o, y_e, y_o) * SCALE       (e = point 2p, o = 2p+1)
// rec[NPAIR+p]  = (z_e, z_o, w_e, w_o), w = -0.5*SCALE*|p|^2
// Seeds FoldX/FoldY coord records once (sink_step rewrites only Z-records).
__global__ __launch_bounds__(256) void pack_geo(
    const float* __restrict__ X, const float* __restrict__ Y,
    v4f* __restrict__ Xg, v4f* __restrict__ Yg,
    v4f* __restrict__ FoldX, v4f* __restrict__ FoldY)
{
    const int b = blockIdx.y;
    const int p = blockIdx.x * 256 + threadIdx.x;
    {
        const float* s = X + (size_t)b * NPTS * 3 + 6 * p;
        float a0=s[0],a1=s[1],a2=s[2],a3=s[3],a4=s[4],a5=s[5];
        float we = -0.5f*SCALE*(a0*a0+a1*a1+a2*a2);
        float wo = -0.5f*SCALE*(a3*a3+a4*a4+a5*a5);
        v4f u; u.x=a0*SCALE; u.y=a3*SCALE; u.z=a1*SCALE; u.w=a4*SCALE;
        v4f v; v.x=a2*SCALE; v.y=a5*SCALE; v.z=we; v.w=wo;
        Xg[(size_t)b*NPTS + p] = u;         Xg[(size_t)b*NPTS + NPAIR + p] = v;
        FoldX[(size_t)b*NPTS + p] = u;      FoldX[(size_t)b*NPTS + NPAIR + p] = v;
    }
    {
        const float* s = Y + (size_t)b * NPTS * 3 + 6 * p;
        float a0=s[0],a1=s[1],a2=s[2],a3=s[3],a4=s[4],a5=s[5];
        float we = -0.5f*SCALE*(a0*a0+a1*a1+a2*a2);
        float wo = -0.5f*SCALE*(a3*a3+a4*a4+a5*a5);
        v4f u; u.x=a0*SCALE; u.y=a3*SCALE; u.z=a1*SCALE; u.w=a4*SCALE;
        v4f v; v.x=a2*SCALE; v.y=a5*SCALE; v.z=we; v.w=wo;
        Yg[(size_t)b*NPTS + p] = u;         Yg[(size_t)b*NPTS + NPAIR + p] = v;
        FoldY[(size_t)b*NPTS + p] = u;      FoldY[(size_t)b*NPTS + NPAIR + p] = v;
    }
}

// One Sinkhorn half-update: 512 threads, 8 row-groups x (1 wave, 4 rows).
// __launch_bounds__(512, 4): 4 blocks/CU (CUDA min-blocks semantics) ->
// 8 waves/SIMD -> 64-VGPR budget; kernel's natural pressure ~44 fits.
__global__ __launch_bounds__(BLK, 4) void sink_step(
    const v4f* __restrict__ geoR, const v4f* __restrict__ stageSrc,
    float* __restrict__ Pout, v4f* __restrict__ FoldOut, float* __restrict__ partA)
{
    __shared__ v4f S[2 * NPAIR];
    __shared__ float gsum[NGRP];
    v4f* PX = S;
    v4f* PZ = S + NPAIR;

    const int b = blockIdx.y, tile = blockIdx.x, tid = threadIdx.x;
    const int sub = tid & (LPR - 1);
    const int grp = tid >> 6;
    const int row0 = tile * RPB + grp * RPT;

    stage_async(stageSrc + (size_t)b * NPTS, S, tid);

    // rows (pristine, pair-packed): pair q holds rows 2q,2q+1
    const v4f* gR = geoR + (size_t)b * NPTS;
    const int q = row0 >> 1;
    v4f A = gR[q], B = gR[NPAIR + q], C = gR[q + 1], D = gR[NPAIR + q + 1];
    v2f xb[RPT], yb[RPT], zb[RPT];
    float a2[RPT], mx[RPT], s[RPT];
    xb[0]=bc2(A.x*INV_SCALE); yb[0]=bc2(A.z*INV_SCALE); zb[0]=bc2(B.x*INV_SCALE); a2[0]=B.z;
    xb[1]=bc2(A.y*INV_SCALE); yb[1]=bc2(A.w*INV_SCALE); zb[1]=bc2(B.y*INV_SCALE); a2[1]=B.w;
    xb[2]=bc2(C.x*INV_SCALE); yb[2]=bc2(C.z*INV_SCALE); zb[2]=bc2(D.x*INV_SCALE); a2[2]=D.z;
    xb[3]=bc2(C.y*INV_SCALE); yb[3]=bc2(C.w*INV_SCALE); zb[3]=bc2(D.y*INV_SCALE); a2[3]=D.w;
    #pragma unroll
    for (int rr = 0; rr < RPT; ++rr) { mx[rr] = NEG_INF; s[rr] = 0.0f; }

    asm volatile("s_waitcnt vmcnt(0)" ::: "memory");
    __syncthreads();

    // online-LSE over 4 column-pairs (8 cols) per iteration, packed math
    #pragma unroll 2
    for (int k = sub; k < NPAIR; k += 4 * LPR) {
        v4f A0 = PX[k],         Z0 = PZ[k];
        v4f A1 = PX[k + LPR],   Z1 = PZ[k + LPR];
        v4f A2 = PX[k + 2*LPR], Z2 = PZ[k + 2*LPR];
        v4f A3 = PX[k + 3*LPR], Z3 = PZ[k + 3*LPR];
        #pragma unroll
        for (int rr = 0; rr < RPT; ++rr) {
            v2f t0 = xb[rr]*A0.xy + yb[rr]*A0.zw + zb[rr]*Z0.xy + Z0.zw;
            v2f t1 = xb[rr]*A1.xy + yb[rr]*A1.zw + zb[rr]*Z1.xy + Z1.zw;
            v2f t2 = xb[rr]*A2.xy + yb[rr]*A2.zw + zb[rr]*Z2.xy + Z2.zw;
            v2f t3 = xb[rr]*A3.xy + yb[rr]*A3.zw + zb[rr]*Z3.xy + Z3.zw;
            v2f cm = vmax2(vmax2(t0, t1), vmax2(t2, t3));
            float mc = fmaxf(cm.x, cm.y);
            float nm = fmaxf(mx[rr], mc);
            float er = exp2fast(mx[rr] - nm);
            v2f nm2 = bc2(nm);
            v2f u0 = t0 - nm2, u1 = t1 - nm2, u2 = t2 - nm2, u3 = t3 - nm2;
            float e0 = exp2fast(u0.x), e1 = exp2fast(u0.y);
            float e2 = exp2fast(u1.x), e3 = exp2fast(u1.y);
            float e4 = exp2fast(u2.x), e5 = exp2fast(u2.y);
            float e6 = exp2fast(u3.x), e7 = exp2fast(u3.y);
            s[rr]  = fmaf(s[rr], er, ((e0+e1)+(e2+e3)) + ((e4+e5)+(e6+e7)));
            mx[rr] = nm;
        }
    }

    // two-phase merge across 64 lanes: max-reduce, one rescale, sum-reduce
    float om[RPT];
    #pragma unroll
    for (int rr = 0; rr < RPT; ++rr) om[rr] = mx[rr];
    #pragma unroll
    for (int d = 1; d < LPR; d <<= 1) {
        #pragma unroll
        for (int rr = 0; rr < RPT; ++rr) mx[rr] = fmaxf(mx[rr], __shfl_xor(mx[rr], d));
    }
    #pragma unroll
    for (int rr = 0; rr < RPT; ++rr) s[rr] *= exp2fast(om[rr] - mx[rr]);
    #pragma unroll
    for (int d = 1; d < LPR; d <<= 1) {
        #pragma unroll
        for (int rr = 0; rr < RPT; ++rr) s[rr] += __shfl_xor(s[rr], d);
    }

    if (sub == 0) {
        float pot[RPT];
        #pragma unroll
        for (int rr = 0; rr < RPT; ++rr)
            pot[rr] = EPS * (LN_N - LN2 * (a2[rr] + mx[rr] + log2fast(s[rr])));
        v4f pv; pv.x = pot[0]; pv.y = pot[1]; pv.z = pot[2]; pv.w = pot[3];
        *(v4f*)(Pout + (size_t)b * NPTS + row0) = pv;     // row0 % 4 == 0

        // fold-forward: only the 2 changed Z-records (coords seeded by pack_geo)
        v4f* fo = FoldOut + (size_t)b * NPTS;
        v4f u;
        u.x = zb[0].x*SCALE; u.y = zb[1].x*SCALE;
        u.z = fmaf(pot[0], SCALE, a2[0]); u.w = fmaf(pot[1], SCALE, a2[1]);
        fo[NPAIR + q] = u;
        u.x = zb[2].x*SCALE; u.y = zb[3].x*SCALE;
        u.z = fmaf(pot[2], SCALE, a2[2]); u.w = fmaf(pot[3], SCALE, a2[3]);
        fo[NPAIR + q + 1] = u;

        if (partA) {
            float c = 0.0f;
            #pragma unroll
            for (int rr = 0; rr < RPT; ++rr)
                c += fmaxf(-2.0f * INV_SCALE * (a2[rr] + mx[rr]), 0.0f);
            gsum[grp] = c;
        }
    }
    if (partA) {
        __syncthreads();
        if (tid == 0) {
            float t = 0.0f;
            #pragma unroll
            for (int i = 0; i < NGRP; ++i) t += gsum[i];
            partA[b * GRID_X + tile] = t;
        }
    }
}

// Chamfer dir-B: rows = Y pristine, cols = X pristine. Max-only scan.
__global__ __launch_bounds__(BLK, 4) void chamfer_b(
    const v4f* __restrict__ geoR, const v4f* __restrict__ stageSrc,
    float* __restrict__ part)
{
    __shared__ v4f S[2 * NPAIR];
    __shared__ float gsum[NGRP];
    v4f* PX = S;
    v4f* PZ = S + NPAIR;
    const int b = blockIdx.y, tile = blockIdx.x, tid = threadIdx.x;
    const int sub = tid & (LPR - 1);
    const int grp = tid >> 6;
    const int row0 = tile * RPB + grp * RPT;

    stage_async(stageSrc + (size_t)b * NPTS, S, tid);

    const v4f* gR = geoR + (size_t)b * NPTS;
    const int q = row0 >> 1;
    v4f A = gR[q], B = gR[NPAIR + q], C = gR[q + 1], D = gR[NPAIR + q + 1];
    v2f xb[RPT], yb[RPT], zb[RPT];
    float a2[RPT], mx[RPT];
    xb[0]=bc2(A.x*INV_SCALE); yb[0]=bc2(A.z*INV_SCALE); zb[0]=bc2(B.x*INV_SCALE); a2[0]=B.z;
    xb[1]=bc2(A.y*INV_SCALE); yb[1]=bc2(A.w*INV_SCALE); zb[1]=bc2(B.y*INV_SCALE); a2[1]=B.w;
    xb[2]=bc2(C.x*INV_SCALE); yb[2]=bc2(C.z*INV_SCALE); zb[2]=bc2(D.x*INV_SCALE); a2[2]=D.z;
    xb[3]=bc2(C.y*INV_SCALE); yb[3]=bc2(C.w*INV_SCALE); zb[3]=bc2(D.y*INV_SCALE); a2[3]=D.w;
    #pragma unroll
    for (int rr = 0; rr < RPT; ++rr) mx[rr] = NEG_INF;

    asm volatile("s_waitcnt vmcnt(0)" ::: "memory");
    __syncthreads();

    #pragma unroll 2
    for (int k = sub; k < NPAIR; k += 4 * LPR) {
        v4f A0 = PX[k],         Z0 = PZ[k];
        v4f A1 = PX[k + LPR],   Z1 = PZ[k + LPR];
        v4f A2 = PX[k + 2*LPR], Z2 = PZ[k + 2*LPR];
        v4f A3 = PX[k + 3*LPR], Z3 = PZ[k + 3*LPR];
        #pragma unroll
        for (int rr = 0; rr < RPT; ++rr) {
            v2f t0 = xb[rr]*A0.xy + yb[rr]*A0.zw + zb[rr]*Z0.xy + Z0.zw;
            v2f t1 = xb[rr]*A1.xy + yb[rr]*A1.zw + zb[rr]*Z1.xy + Z1.zw;
            v2f t2 = xb[rr]*A2.xy + yb[rr]*A2.zw + zb[rr]*Z2.xy + Z2.zw;
            v2f t3 = xb[rr]*A3.xy + yb[rr]*A3.zw + zb[rr]*Z3.xy + Z3.zw;
            v2f cm = vmax2(vmax2(t0, t1), vmax2(t2, t3));
            mx[rr] = fmaxf(mx[rr], fmaxf(cm.x, cm.y));
        }
    }
    #pragma unroll
    for (int d = 1; d < LPR; d <<= 1) {
        #pragma unroll
        for (int rr = 0; rr < RPT; ++rr) mx[rr] = fmaxf(mx[rr], __shfl_xor(mx[rr], d));
    }
    if (sub == 0) {
        float c = 0.0f;
        #pragma unroll
        for (int rr = 0; rr < RPT; ++rr)
            c += fmaxf(-2.0f * INV_SCALE * (a2[rr] + mx[rr]), 0.0f);
        gsum[grp] = c;
    }
    __syncthreads();
    if (tid == 0) {
        float t = 0.0f;
        #pragma unroll
        for (int i = 0; i < NGRP; ++i) t += gsum[i];
        part[b * GRID_X + tile] = t;
    }
}

__global__ void finalize(const float* __restrict__ F, const float* __restrict__ G,
                         const float* __restrict__ part, float* __restrict__ out)
{
    const int b = blockIdx.x, tid = threadIdx.x;
    float sf = 0.0f, sg = 0.0f, sc = 0.0f;
    for (int i = tid; i < NPTS; i += 256) {
        sf += F[(size_t)b * NPTS + i];
        sg += G[(size_t)b * NPTS + i];
    }
    for (int i = tid; i < 2 * GRID_X * BATCH; i += 256) sc += part[i];
    #pragma unroll
    for (int d = 1; d < 64; d <<= 1) {
        sf += __shfl_xor(sf, d); sg += __shfl_xor(sg, d); sc += __shfl_xor(sc, d);
    }
    __shared__ float wf[4], wg[4], wc[4];
    const int w = tid >> 6;
    if ((tid & 63) == 0) { wf[w] = sf; wg[w] = sg; wc[w] = sc; }
    __syncthreads();
    if (tid == 0) {
        float tf = wf[0] + wf[1] + wf[2] + wf[3];
        float tg = wg[0] + wg[1] + wg[2] + wg[3];
        float tc = wc[0] + wc[1] + wc[2] + wc[3];
        float emd = (tf + tg) * (1.0f / NPTS);
        float cd  = tc * (1.0f / (BATCH * NPTS));
        out[b] = 0.5f * cd + 0.5f * emd;
    }
}

extern "C" void kernel_launch(void* const* d_in, const int* in_sizes, int n_in,
                              void* d_out, int out_size, void* d_ws, size_t ws_size,
                              hipStream_t stream)
{
    const float* Xtrue = (const float*)d_in[0];   // y_true: rows of D
    const float* Ypred = (const float*)d_in[1];   // y_pred: cols of D

    float* F    = (float*)d_ws;                   // [16][2048]
    float* G    = F + BATCH * NPTS;               // [16][2048]
    float* part = G + BATCH * NPTS;               // [2048]
    v4f*  Xg    = (v4f*)(part + 2 * GRID_X * BATCH);   // 16B-aligned
    v4f*  Yg    = Xg + (size_t)BATCH * NPTS;
    v4f*  FoldX = Yg + (size_t)BATCH * NPTS;
    v4f*  FoldY = FoldX + (size_t)BATCH * NPTS;

    pack_geo<<<dim3(NPAIR / 256, BATCH), dim3(256), 0, stream>>>(
        Xtrue, Ypred, Xg, Yg, FoldX, FoldY);

    dim3 grid(GRID_X, BATCH), blk(BLK);
    chamfer_b<<<grid, blk, 0, stream>>>(Yg, Xg, part + GRID_X * BATCH);

    // iter 0: f-update stages pristine Yg (pot=0) and emits chamfer dir-A
    sink_step<<<grid, blk, 0, stream>>>(Xg, Yg, F, FoldX, part);
    sink_step<<<grid, blk, 0, stream>>>(Yg, FoldX, G, FoldY, nullptr);
    for (int it = 1; it < ITERS; ++it) {
        sink_step<<<grid, blk, 0, stream>>>(Xg, FoldY, F, FoldX, nullptr);
        sink_step<<<grid, blk, 0, stream>>>(Yg, FoldX, G, FoldY, nullptr);
    }
    finalize<<<dim3(BATCH), dim3(256), 0, stream>>>(F, G, part, (float*)d_out);
}

// Round 10
// 1537.864 us; speedup vs baseline: 8.7324x; 1.3986x over previous
//
#include <hip/hip_runtime.h>
#include <math.h>

typedef float v2f __attribute__((ext_vector_type(2)));
typedef float v4f __attribute__((ext_vector_type(4)));

#define NPTS   2048
#define NPAIR  1024
#define BATCH  16
#define EPS    0.0025f                      // blur=0.05, p=2 -> eps = 0.05^2
#define SCALE  577.0780163555853f           // (1/EPS) * log2(e)
#define INV_SCALE (1.0f / SCALE)
#define LN2    0.6931471805599453f
#define LN_N   7.6246189861593985f          // ln(2048)
#define ITERS  50
#define RPT    4                            // rows per thread
#define LPR    32                           // lanes per row
#define RPB    32                           // rows per block
#define GRID_X (NPTS / RPB)                 // 64 -> 1024 blocks = 4/CU
#define NEG_INF (-3.0e38f)

__device__ __forceinline__ float exp2fast(float x) { return __builtin_amdgcn_exp2f(x); }
__device__ __forceinline__ float log2fast(float x) { return __builtin_amdgcn_logf(x); }
__device__ __forceinline__ v2f bc2(float v) { v2f r; r.x = v; r.y = v; return r; }
__device__ __forceinline__ v2f vmax2(v2f a, v2f b) { return __builtin_elementwise_max(a, b); }

// Async global->LDS staging of 2048 v4f (32 KB), linear, wave-uniform LDS base.
__device__ __forceinline__ void stage_async(const v4f* __restrict__ src, v4f* dst, int tid)
{
    const int lane = tid & 63;
    const int wid  = tid >> 6;
    #pragma unroll
    for (int i = 0; i < 8; ++i) {
        const int m0 = i * 256 + wid * 64;
        __builtin_amdgcn_global_load_lds(
            (const __attribute__((address_space(1))) void*)(src + m0 + lane),
            (__attribute__((address_space(3))) void*)(dst + m0), 16, 0, 0);
    }
}

// Pair-interleaved packing:
// rec[p]        = (x_e, x_o, y_e, y_o) * SCALE       (e = point 2p, o = 2p+1)
// rec[NPAIR+p]  = (z_e, z_o, w_e, w_o), w = -0.5*SCALE*|p|^2
// Seeds FoldX/FoldY coord records once (sink_step rewrites only Z-records).
__global__ __launch_bounds__(256) void pack_geo(
    const float* __restrict__ X, const float* __restrict__ Y,
    v4f* __restrict__ Xg, v4f* __restrict__ Yg,
    v4f* __restrict__ FoldX, v4f* __restrict__ FoldY)
{
    const int b = blockIdx.y;
    const int p = blockIdx.x * 256 + threadIdx.x;
    {
        const float* s = X + (size_t)b * NPTS * 3 + 6 * p;
        float a0=s[0],a1=s[1],a2=s[2],a3=s[3],a4=s[4],a5=s[5];
        float we = -0.5f*SCALE*(a0*a0+a1*a1+a2*a2);
        float wo = -0.5f*SCALE*(a3*a3+a4*a4+a5*a5);
        v4f u; u.x=a0*SCALE; u.y=a3*SCALE; u.z=a1*SCALE; u.w=a4*SCALE;
        v4f v; v.x=a2*SCALE; v.y=a5*SCALE; v.z=we; v.w=wo;
        Xg[(size_t)b*NPTS + p] = u;         Xg[(size_t)b*NPTS + NPAIR + p] = v;
        FoldX[(size_t)b*NPTS + p] = u;      FoldX[(size_t)b*NPTS + NPAIR + p] = v;
    }
    {
        const float* s = Y + (size_t)b * NPTS * 3 + 6 * p;
        float a0=s[0],a1=s[1],a2=s[2],a3=s[3],a4=s[4],a5=s[5];
        float we = -0.5f*SCALE*(a0*a0+a1*a1+a2*a2);
        float wo = -0.5f*SCALE*(a3*a3+a4*a4+a5*a5);
        v4f u; u.x=a0*SCALE; u.y=a3*SCALE; u.z=a1*SCALE; u.w=a4*SCALE;
        v4f v; v.x=a2*SCALE; v.y=a5*SCALE; v.z=we; v.w=wo;
        Yg[(size_t)b*NPTS + p] = u;         Yg[(size_t)b*NPTS + NPAIR + p] = v;
        FoldY[(size_t)b*NPTS + p] = u;      FoldY[(size_t)b*NPTS + NPAIR + p] = v;
    }
}

// One Sinkhorn half-update (RPT=4, LPR=32, 256 threads, 44 VGPR, no spill).
// Rows from pristine geoR; cols staged (async DMA) from stageSrc whose .w
// already folds the current potential. Writes potentials Pout and the 2
// changed Z-records of FoldOut (next dispatch's staging source).
// partA != nullptr (first f-update, pristine cols): emit chamfer dir-A partials.
__global__ __launch_bounds__(256, 4) void sink_step(
    const v4f* __restrict__ geoR, const v4f* __restrict__ stageSrc,
    float* __restrict__ Pout, v4f* __restrict__ FoldOut, float* __restrict__ partA)
{
    __shared__ v4f S[2 * NPAIR];
    __shared__ float gsum[8];
    v4f* PX = S;
    v4f* PZ = S + NPAIR;

    const int b = blockIdx.y, tile = blockIdx.x, tid = threadIdx.x;
    const int sub = tid & (LPR - 1);
    const int grp = tid >> 5;
    const int row0 = tile * RPB + grp * RPT;

    stage_async(stageSrc + (size_t)b * NPTS, S, tid);

    // rows (pristine, pair-packed): pair q holds rows 2q,2q+1
    const v4f* gR = geoR + (size_t)b * NPTS;
    const int q = row0 >> 1;
    v4f A = gR[q], B = gR[NPAIR + q], C = gR[q + 1], D = gR[NPAIR + q + 1];
    v2f xb[RPT], yb[RPT], zb[RPT];
    float a2[RPT], mx[RPT], s[RPT];
    xb[0]=bc2(A.x*INV_SCALE); yb[0]=bc2(A.z*INV_SCALE); zb[0]=bc2(B.x*INV_SCALE); a2[0]=B.z;
    xb[1]=bc2(A.y*INV_SCALE); yb[1]=bc2(A.w*INV_SCALE); zb[1]=bc2(B.y*INV_SCALE); a2[1]=B.w;
    xb[2]=bc2(C.x*INV_SCALE); yb[2]=bc2(C.z*INV_SCALE); zb[2]=bc2(D.x*INV_SCALE); a2[2]=D.z;
    xb[3]=bc2(C.y*INV_SCALE); yb[3]=bc2(C.w*INV_SCALE); zb[3]=bc2(D.y*INV_SCALE); a2[3]=D.w;
    #pragma unroll
    for (int rr = 0; rr < RPT; ++rr) { mx[rr] = NEG_INF; s[rr] = 0.0f; }

    asm volatile("s_waitcnt vmcnt(0)" ::: "memory");
    __syncthreads();

    // online-LSE over 4 column-pairs (8 cols) per iteration, packed math
    #pragma unroll 2
    for (int k = sub; k < NPAIR; k += 4 * LPR) {
        v4f A0 = PX[k],         Z0 = PZ[k];
        v4f A1 = PX[k + LPR],   Z1 = PZ[k + LPR];
        v4f A2 = PX[k + 2*LPR], Z2 = PZ[k + 2*LPR];
        v4f A3 = PX[k + 3*LPR], Z3 = PZ[k + 3*LPR];
        #pragma unroll
        for (int rr = 0; rr < RPT; ++rr) {
            v2f t0 = xb[rr]*A0.xy + yb[rr]*A0.zw + zb[rr]*Z0.xy + Z0.zw;
            v2f t1 = xb[rr]*A1.xy + yb[rr]*A1.zw + zb[rr]*Z1.xy + Z1.zw;
            v2f t2 = xb[rr]*A2.xy + yb[rr]*A2.zw + zb[rr]*Z2.xy + Z2.zw;
            v2f t3 = xb[rr]*A3.xy + yb[rr]*A3.zw + zb[rr]*Z3.xy + Z3.zw;
            v2f cm = vmax2(vmax2(t0, t1), vmax2(t2, t3));
            float mc = fmaxf(cm.x, cm.y);
            float nm = fmaxf(mx[rr], mc);
            float er = exp2fast(mx[rr] - nm);
            v2f nm2 = bc2(nm);
            v2f u0 = t0 - nm2, u1 = t1 - nm2, u2 = t2 - nm2, u3 = t3 - nm2;
            float e0 = exp2fast(u0.x), e1 = exp2fast(u0.y);
            float e2 = exp2fast(u1.x), e3 = exp2fast(u1.y);
            float e4 = exp2fast(u2.x), e5 = exp2fast(u2.y);
            float e6 = exp2fast(u3.x), e7 = exp2fast(u3.y);
            s[rr]  = fmaf(s[rr], er, ((e0+e1)+(e2+e3)) + ((e4+e5)+(e6+e7)));
            mx[rr] = nm;
        }
    }

    // two-phase merge across 32 lanes: max-reduce, one rescale, sum-reduce
    float om[RPT];
    #pragma unroll
    for (int rr = 0; rr < RPT; ++rr) om[rr] = mx[rr];
    #pragma unroll
    for (int d = 1; d < LPR; d <<= 1) {
        #pragma unroll
        for (int rr = 0; rr < RPT; ++rr) mx[rr] = fmaxf(mx[rr], __shfl_xor(mx[rr], d));
    }
    #pragma unroll
    for (int rr = 0; rr < RPT; ++rr) s[rr] *= exp2fast(om[rr] - mx[rr]);
    #pragma unroll
    for (int d = 1; d < LPR; d <<= 1) {
        #pragma unroll
        for (int rr = 0; rr < RPT; ++rr) s[rr] += __shfl_xor(s[rr], d);
    }

    if (sub == 0) {
        float pot[RPT];
        #pragma unroll
        for (int rr = 0; rr < RPT; ++rr)
            pot[rr] = EPS * (LN_N - LN2 * (a2[rr] + mx[rr] + log2fast(s[rr])));
        float* dp = Pout + (size_t)b * NPTS + row0;
        dp[0] = pot[0]; dp[1] = pot[1]; dp[2] = pot[2]; dp[3] = pot[3];

        // fold-forward: only the 2 changed Z-records (coords seeded by pack_geo)
        v4f* fo = FoldOut + (size_t)b * NPTS;
        v4f u;
        u.x = zb[0].x*SCALE; u.y = zb[1].x*SCALE;
        u.z = fmaf(pot[0], SCALE, a2[0]); u.w = fmaf(pot[1], SCALE, a2[1]);
        fo[NPAIR + q] = u;
        u.x = zb[2].x*SCALE; u.y = zb[3].x*SCALE;
        u.z = fmaf(pot[2], SCALE, a2[2]); u.w = fmaf(pot[3], SCALE, a2[3]);
        fo[NPAIR + q + 1] = u;

        if (partA) {
            float c = 0.0f;
            #pragma unroll
            for (int rr = 0; rr < RPT; ++rr)
                c += fmaxf(-2.0f * INV_SCALE * (a2[rr] + mx[rr]), 0.0f);
            gsum[grp] = c;
        }
    }
    if (partA) {
        __syncthreads();
        if (tid == 0) {
            float t = 0.0f;
            #pragma unroll
            for (int i = 0; i < 8; ++i) t += gsum[i];
            partA[b * GRID_X + tile] = t;
        }
    }
}

// Chamfer dir-B: rows = Y pristine, cols = X pristine. Max-only scan.
__global__ __launch_bounds__(256, 4) void chamfer_b(
    const v4f* __restrict__ geoR, const v4f* __restrict__ stageSrc,
    float* __restrict__ part)
{
    __shared__ v4f S[2 * NPAIR];
    __shared__ float gsum[8];
    v4f* PX = S;
    v4f* PZ = S + NPAIR;
    const int b = blockIdx.y, tile = blockIdx.x, tid = threadIdx.x;
    const int sub = tid & (LPR - 1);
    const int grp = tid >> 5;
    const int row0 = tile * RPB + grp * RPT;

    stage_async(stageSrc + (size_t)b * NPTS, S, tid);

    const v4f* gR = geoR + (size_t)b * NPTS;
    const int q = row0 >> 1;
    v4f A = gR[q], B = gR[NPAIR + q], C = gR[q + 1], D = gR[NPAIR + q + 1];
    v2f xb[RPT], yb[RPT], zb[RPT];
    float a2[RPT], mx[RPT];
    xb[0]=bc2(A.x*INV_SCALE); yb[0]=bc2(A.z*INV_SCALE); zb[0]=bc2(B.x*INV_SCALE); a2[0]=B.z;
    xb[1]=bc2(A.y*INV_SCALE); yb[1]=bc2(A.w*INV_SCALE); zb[1]=bc2(B.y*INV_SCALE); a2[1]=B.w;
    xb[2]=bc2(C.x*INV_SCALE); yb[2]=bc2(C.z*INV_SCALE); zb[2]=bc2(D.x*INV_SCALE); a2[2]=D.z;
    xb[3]=bc2(C.y*INV_SCALE); yb[3]=bc2(C.w*INV_SCALE); zb[3]=bc2(D.y*INV_SCALE); a2[3]=D.w;
    #pragma unroll
    for (int rr = 0; rr < RPT; ++rr) mx[rr] = NEG_INF;

    asm volatile("s_waitcnt vmcnt(0)" ::: "memory");
    __syncthreads();

    #pragma unroll 2
    for (int k = sub; k < NPAIR; k += 4 * LPR) {
        v4f A0 = PX[k],         Z0 = PZ[k];
        v4f A1 = PX[k + LPR],   Z1 = PZ[k + LPR];
        v4f A2 = PX[k + 2*LPR], Z2 = PZ[k + 2*LPR];
        v4f A3 = PX[k + 3*LPR], Z3 = PZ[k + 3*LPR];
        #pragma unroll
        for (int rr = 0; rr < RPT; ++rr) {
            v2f t0 = xb[rr]*A0.xy + yb[rr]*A0.zw + zb[rr]*Z0.xy + Z0.zw;
            v2f t1 = xb[rr]*A1.xy + yb[rr]*A1.zw + zb[rr]*Z1.xy + Z1.zw;
            v2f t2 = xb[rr]*A2.xy + yb[rr]*A2.zw + zb[rr]*Z2.xy + Z2.zw;
            v2f t3 = xb[rr]*A3.xy + yb[rr]*A3.zw + zb[rr]*Z3.xy + Z3.zw;
            v2f cm = vmax2(vmax2(t0, t1), vmax2(t2, t3));
            mx[rr] = fmaxf(mx[rr], fmaxf(cm.x, cm.y));
        }
    }
    #pragma unroll
    for (int d = 1; d < LPR; d <<= 1) {
        #pragma unroll
        for (int rr = 0; rr < RPT; ++rr) mx[rr] = fmaxf(mx[rr], __shfl_xor(mx[rr], d));
    }
    if (sub == 0) {
        float c = 0.0f;
        #pragma unroll
        for (int rr = 0; rr < RPT; ++rr)
            c += fmaxf(-2.0f * INV_SCALE * (a2[rr] + mx[rr]), 0.0f);
        gsum[grp] = c;
    }
    __syncthreads();
    if (tid == 0) {
        float t = 0.0f;
        #pragma unroll
        for (int i = 0; i < 8; ++i) t += gsum[i];
        part[b * GRID_X + tile] = t;
    }
}

__global__ void finalize(const float* __restrict__ F, const float* __restrict__ G,
                         const float* __restrict__ part, float* __restrict__ out)
{
    const int b = blockIdx.x, tid = threadIdx.x;
    float sf = 0.0f, sg = 0.0f, sc = 0.0f;
    for (int i = tid; i < NPTS; i += 256) {
        sf += F[(size_t)b * NPTS + i];
        sg += G[(size_t)b * NPTS + i];
    }
    for (int i = tid; i < 2 * GRID_X * BATCH; i += 256) sc += part[i];
    #pragma unroll
    for (int d = 1; d < 64; d <<= 1) {
        sf += __shfl_xor(sf, d); sg += __shfl_xor(sg, d); sc += __shfl_xor(sc, d);
    }
    __shared__ float wf[4], wg[4], wc[4];
    const int w = tid >> 6;
    if ((tid & 63) == 0) { wf[w] = sf; wg[w] = sg; wc[w] = sc; }
    __syncthreads();
    if (tid == 0) {
        float tf = wf[0] + wf[1] + wf[2] + wf[3];
        float tg = wg[0] + wg[1] + wg[2] + wg[3];
        float tc = wc[0] + wc[1] + wc[2] + wc[3];
        float emd = (tf + tg) * (1.0f / NPTS);
        float cd  = tc * (1.0f / (BATCH * NPTS));
        out[b] = 0.5f * cd + 0.5f * emd;
    }
}

extern "C" void kernel_launch(void* const* d_in, const int* in_sizes, int n_in,
                              void* d_out, int out_size, void* d_ws, size_t ws_size,
                              hipStream_t stream)
{
    const float* Xtrue = (const float*)d_in[0];   // y_true: rows of D
    const float* Ypred = (const float*)d_in[1];   // y_pred: cols of D

    float* F    = (float*)d_ws;                   // [16][2048]
    float* G    = F + BATCH * NPTS;               // [16][2048]
    float* part = G + BATCH * NPTS;               // [2048]
    v4f*  Xg    = (v4f*)(part + 2 * GRID_X * BATCH);   // 16B-aligned
    v4f*  Yg    = Xg + (size_t)BATCH * NPTS;
    v4f*  FoldX = Yg + (size_t)BATCH * NPTS;
    v4f*  FoldY = FoldX + (size_t)BATCH * NPTS;

    pack_geo<<<dim3(NPAIR / 256, BATCH), dim3(256), 0, stream>>>(
        Xtrue, Ypred, Xg, Yg, FoldX, FoldY);

    dim3 grid(GRID_X, BATCH), blk(256);
    chamfer_b<<<grid, blk, 0, stream>>>(Yg, Xg, part + GRID_X * BATCH);

    // iter 0: f-update stages pristine Yg (pot=0) and emits chamfer dir-A
    sink_step<<<grid, blk, 0, stream>>>(Xg, Yg, F, FoldX, part);
    sink_step<<<grid, blk, 0, stream>>>(Yg, FoldX, G, FoldY, nullptr);
    for (int it = 1; it < ITERS; ++it) {
        sink_step<<<grid, blk, 0, stream>>>(Xg, FoldY, F, FoldX, nullptr);
        sink_step<<<grid, blk, 0, stream>>>(Yg, FoldX, G, FoldY, nullptr);
    }
    finalize<<<dim3(BATCH), dim3(256), 0, stream>>>(F, G, part, (float*)d_out);
}